// Round 9
// baseline (299.798 us; speedup 1.0000x reference)
//
#include <hip/hip_runtime.h>
#include <hip/hip_bf16.h>

using bf16 = __hip_bfloat16;
typedef __attribute__((ext_vector_type(8))) short s8v;   // 8 x bf16 bits (A/B frag)
typedef __attribute__((ext_vector_type(4))) short s4v;
typedef __attribute__((ext_vector_type(4))) float f32x4; // C/D frag

#define DEV __device__ __forceinline__

DEV f32x4 mfma16(s8v a, s8v b, f32x4 c) {
    return __builtin_amdgcn_mfma_f32_16x16x32_bf16(a, b, c, 0, 0, 0);
}

DEV void gl_to_lds16(const bf16* g, bf16* l) {
    __builtin_amdgcn_global_load_lds(
        (const __attribute__((address_space(1))) void*)g,
        (__attribute__((address_space(3))) void*)l, 16, 0, 0);
}

DEV unsigned short bfbits(bf16 h) { union { bf16 h; unsigned short u; } c; c.h = h; return c.u; }
DEV unsigned pk2(float a, float b) {
    return (unsigned)bfbits(__float2bfloat16(a)) | ((unsigned)bfbits(__float2bfloat16(b)) << 16);
}
// truncation pack (round-toward-zero): 1-2 VALU; fine for nonneg P vs 2% tolerance
DEV unsigned pk2t(float a, float b) {
    return (__float_as_uint(a) >> 16) | (__float_as_uint(b) & 0xffff0000u);
}
DEV void unpk8(uint4 u, float* x) {
    const unsigned uu[4] = {u.x, u.y, u.z, u.w};
#pragma unroll
    for (int j = 0; j < 4; j++) {
        x[2 * j]     = __uint_as_float(uu[j] << 16);
        x[2 * j + 1] = __uint_as_float(uu[j] & 0xffff0000u);
    }
}

// ---------------- fused prep: f32->bf16 converts + conv-weight transpose -----------------
// blocks [0,6656): convert src/Wv/Wo/W1/W2.  blocks [6656,9728): WqT/WkT transpose + zp.
__global__ __launch_bounds__(256)
void prep_all(const float* __restrict__ src, const float* __restrict__ Wv,
              const float* __restrict__ Wo, const float* __restrict__ W1,
              const float* __restrict__ W2, const float* __restrict__ Wq,
              const float* __restrict__ Wk, bf16* __restrict__ srcb,
              bf16* __restrict__ Wvb, bf16* __restrict__ Wob, bf16* __restrict__ W1b,
              bf16* __restrict__ W2b, bf16* __restrict__ WqT, bf16* __restrict__ WkT,
              bf16* __restrict__ zp) {
    const int bid = blockIdx.x;
    if (bid < 6656) {
        const long long i4 = ((long long)bid * 256 + threadIdx.x) * 4;
        const float* in;
        bf16* outp;
        long long off;
        if (i4 < 4194304)      { in = src; outp = srcb; off = 0; }
        else if (i4 < 4456448) { in = Wv;  outp = Wvb;  off = 4194304; }
        else if (i4 < 4718592) { in = Wo;  outp = Wob;  off = 4456448; }
        else if (i4 < 5767168) { in = W1;  outp = W1b;  off = 4718592; }
        else                   { in = W2;  outp = W2b;  off = 5767168; }
        const long long j = i4 - off;
        const float4 v = *(const float4*)(in + j);
        uint2 o;
        o.x = pk2(v.x, v.y);
        o.y = pk2(v.z, v.w);
        *(uint2*)(outp + j) = o;
    } else {
        const int i = (bid - 6656) * 256 + threadIdx.x;
        if (i < 512) zp[i] = __float2bfloat16(0.f);
        const int dk = i >> 18, rem = i & 262143, co = rem >> 9, ci = rem & 511;
        const size_t s = (size_t)co * 1536 + ci * 3 + dk;
        WqT[i] = __float2bfloat16(Wq[s]);
        WkT[i] = __float2bfloat16(Wk[s]);
    }
}

// ---------------- conv Q/K (restructured): stage A once per ci-chunk, 3 dk passes --------
// out[s,co] = sum_{dk,ci} src[s-1+dk,ci]*WT[dk][co][ci] + bias
// Q additionally pre-scaled by log2(e)/64 so attention can use bare exp2.
__global__ __launch_bounds__(256)
void conv_qk(const bf16* __restrict__ src, const bf16* __restrict__ WqT,
             const bf16* __restrict__ WkT, const float* __restrict__ bq,
             const float* __restrict__ bk, bf16* __restrict__ Qo, bf16* __restrict__ Ko,
             const bf16* __restrict__ zp) {
    const int z = blockIdx.z, b = z & 7, isK = z >> 3;
    const bf16* WT = isK ? WkT : WqT;
    const float* bias = isK ? bk : bq;
    bf16* out = isK ? Ko : Qo;
    const float qs = isK ? 1.0f : 0.022542109951390054f;  // log2(e)/64
    const bf16* S = src + ((size_t)b << 19);
    const int m0 = blockIdx.x * 128, n0 = blockIdx.y * 128;
    const int tid = threadIdx.x, w = tid >> 6, l = tid & 63;
    const int lq = l & 15, quad = l >> 4;
    const int wm = (w >> 1) << 6, wn = (w & 1) << 6;
    // As row r <-> src row m0-1+r, r in [0,130); Bs[dk][co][ci]
    __shared__ __align__(16) bf16 As[4224], Bs[12288];
    f32x4 acc[4][4] = {};
    for (int ci0 = 0; ci0 < 512; ci0 += 32) {
        if (ci0) __syncthreads();
        // stage A: 130 rows x 32 ci (two full-wave calls + 8-lane tail)
#pragma unroll
        for (int j = 0; j < 2; j++) {
            const int r = j * 64 + w * 16 + (l >> 2);
            const int srow = m0 - 1 + r;
            const bf16* ga = (srow >= 0 && srow < 1024)
                                 ? S + (size_t)srow * 512 + ci0 + (l & 3) * 8
                                 : zp + (l & 3) * 8;
            gl_to_lds16(ga, &As[(j * 64 + w * 16) * 32]);
        }
        if (tid < 8) {
            const int srow = m0 + 127 + (l >> 2);
            const bf16* ga = (srow < 1024) ? S + (size_t)srow * 512 + ci0 + (l & 3) * 8
                                           : zp + (l & 3) * 8;
            gl_to_lds16(ga, &As[128 * 32]);
        }
        // stage B: 3 dk x 128 co x 32 ci
#pragma unroll
        for (int dk = 0; dk < 3; dk++)
#pragma unroll
            for (int j = 0; j < 2; j++) {
                const int co = n0 + j * 64 + w * 16 + (l >> 2);
                gl_to_lds16(WT + ((size_t)dk << 18) + (size_t)co * 512 + ci0 + (l & 3) * 8,
                            &Bs[dk * 4096 + (j * 64 + w * 16) * 32]);
            }
        __syncthreads();
#pragma unroll
        for (int dk = 0; dk < 3; dk++) {
            s8v af[4], bfv[4];
#pragma unroll
            for (int x = 0; x < 4; x++) {
                af[x]  = *(const s8v*)&As[(wm + x * 16 + lq + dk) * 32 + quad * 8];
                bfv[x] = *(const s8v*)&Bs[dk * 4096 + (wn + x * 16 + lq) * 32 + quad * 8];
            }
#pragma unroll
            for (int mt = 0; mt < 4; mt++)
#pragma unroll
                for (int nt = 0; nt < 4; nt++)
                    acc[mt][nt] = mfma16(af[mt], bfv[nt], acc[mt][nt]);
        }
    }
#pragma unroll
    for (int nt = 0; nt < 4; nt++) {
        const int co = n0 + wn + nt * 16 + lq;
        const float bn = bias[co];
        const size_t obase = ((size_t)b << 19) + ((size_t)(co >> 6) << 16) + (co & 63);
#pragma unroll
        for (int mt = 0; mt < 4; mt++)
#pragma unroll
            for (int r = 0; r < 4; r++) {
                const int s = m0 + wm + mt * 16 + quad * 4 + r;
                out[obase + (size_t)s * 64] = __float2bfloat16((acc[mt][nt][r] + bn) * qs);
            }
    }
}

// ---------------- generic NT GEMM: C[m,n] = sum_k A[m,k]*B[n,k], per-z offsets ------------
// EPI: 1 = bf16 out, bias[n], ReLU;  2 = bf16 out, bias[m];  3 = f32 partial, no bias
template <int EPI>
__global__ __launch_bounds__(256)
void gemm_nt(const bf16* __restrict__ A, const bf16* __restrict__ B,
             const float* __restrict__ bias, void* __restrict__ C, int M, int N, int K,
             int lda, int ldb, int ldc, long long aOff, long long bOff, long long cOff) {
    const int m0 = blockIdx.x * 128, n0 = blockIdx.y * 128, z = blockIdx.z;
    A += (size_t)z * aOff;
    B += (size_t)z * bOff;
    const int tid = threadIdx.x, w = tid >> 6, l = tid & 63;
    const int wm = (w >> 1) << 6, wn = (w & 1) << 6;
    __shared__ __align__(16) bf16 As[4096], Bs[4096];
    f32x4 acc[4][4] = {};
    for (int k0 = 0; k0 < K; k0 += 32) {
        if (k0) __syncthreads();
#pragma unroll
        for (int i = 0; i < 2; i++) {
            gl_to_lds16(A + (size_t)(m0 + i * 64 + w * 16 + (l >> 2)) * lda + k0 + (l & 3) * 8,
                        &As[i * 2048 + w * 512]);
            gl_to_lds16(B + (size_t)(n0 + i * 64 + w * 16 + (l >> 2)) * ldb + k0 + (l & 3) * 8,
                        &Bs[i * 2048 + w * 512]);
        }
        __syncthreads();
        s8v af[4], bfv[4];
#pragma unroll
        for (int x = 0; x < 4; x++) {
            af[x]  = *(const s8v*)&As[(wm + x * 16 + (l & 15)) * 32 + ((l >> 4) << 3)];
            bfv[x] = *(const s8v*)&Bs[(wn + x * 16 + (l & 15)) * 32 + ((l >> 4) << 3)];
        }
#pragma unroll
        for (int mt = 0; mt < 4; mt++)
#pragma unroll
            for (int nt = 0; nt < 4; nt++) acc[mt][nt] = mfma16(af[mt], bfv[nt], acc[mt][nt]);
    }
#pragma unroll
    for (int nt = 0; nt < 4; nt++) {
        const int n = n0 + wn + nt * 16 + (l & 15);
        const float bn = (EPI == 1) ? bias[n] : 0.f;
#pragma unroll
        for (int mt = 0; mt < 4; mt++)
#pragma unroll
            for (int r = 0; r < 4; r++) {
                const int m = m0 + wm + mt * 16 + ((l >> 4) << 2) + r;
                float v = acc[mt][nt][r];
                const size_t off = (size_t)z * cOff + (size_t)m * ldc + n;
                if (EPI == 3) {
                    ((float*)C)[off] = v;
                } else {
                    v += (EPI == 2) ? bias[m] : bn;
                    if (EPI == 1) v = fmaxf(v, 0.f);
                    ((bf16*)C)[off] = __float2bfloat16(v);
                }
            }
    }
}

// ---------------- flash attention: barrier-free, direct-global K/V fragments -------------
// S^T = K·Q^T (Q pre-scaled by log2e/64): p = exp2(s). O^T = V^T·P^T.
// K [t][d] and V [d][t] are already in MFMA A-fragment layout for direct 16B global
// loads -> no LDS staging, no __syncthreads. Only P round-trips LDS (per-wave, FIFO).
// 4 waves/block share the same K/V tile -> L1-resident (2 blocks/CU x 16KB = 32KB L1).
__global__ __launch_bounds__(256)
void attn_kernel(const bf16* __restrict__ Q, const bf16* __restrict__ K,
                 const bf16* __restrict__ V, bf16* __restrict__ av) {
    const int bh = blockIdx.x, b = bh >> 3, h = bh & 7;
    const bf16* Qp = Q + ((size_t)bh << 16);  // [1024 q][64 d]
    const bf16* Kp = K + ((size_t)bh << 16);  // [1024 t][64 d]
    const bf16* Vp = V + ((size_t)bh << 16);  // [64 d][1024 t]
    const int tid = threadIdx.x, w = tid >> 6, l = tid & 63;
    const int lq = l & 15, quad = l >> 4;
    const int q0 = blockIdx.y * 128 + w * 16;   // frag0: q0, frag1: q0+64
    __shared__ __align__(16) bf16 Ps[8192];     // per-wave P, XOR-swizzled
    bf16* Pw0 = &Ps[(w * 2 + 0) * 1024];
    bf16* Pw1 = &Ps[(w * 2 + 1) * 1024];
    const s8v qf00 = *(const s8v*)&Qp[(size_t)(q0 + lq) * 64 + quad * 8];
    const s8v qf01 = *(const s8v*)&Qp[(size_t)(q0 + lq) * 64 + 32 + quad * 8];
    const s8v qf10 = *(const s8v*)&Qp[(size_t)(q0 + 64 + lq) * 64 + quad * 8];
    const s8v qf11 = *(const s8v*)&Qp[(size_t)(q0 + 64 + lq) * 64 + 32 + quad * 8];
    f32x4 o0[4] = {}, o1[4] = {};
    float l0 = 0.f, l1 = 0.f;
    const int rdz0 = (quad ^ (lq & 7)) * 8;        // P frag read, cols 0..31
    const int rdz1 = ((quad + 4) ^ (lq & 7)) * 8;  // P frag read, cols 32..63
    const int pwz = ((quad >> 1) ^ (lq & 7)) * 8 + (quad & 1) * 4;  // P-write base (tt=0)
    for (int t0 = 0; t0 < 1024; t0 += 64) {
        f32x4 st0[4] = {}, st1[4] = {};
#pragma unroll
        for (int tt = 0; tt < 4; tt++) {
            const bf16* kr = &Kp[(size_t)(t0 + tt * 16 + lq) * 64];
            const s8v ka0 = *(const s8v*)&kr[quad * 8];
            const s8v ka1 = *(const s8v*)&kr[32 + quad * 8];
            st0[tt] = mfma16(ka0, qf00, st0[tt]);
            st0[tt] = mfma16(ka1, qf01, st0[tt]);
            st1[tt] = mfma16(ka0, qf10, st1[tt]);
            st1[tt] = mfma16(ka1, qf11, st1[tt]);
        }
        float cs0 = 0.f, cs1 = 0.f;
#pragma unroll
        for (int tt = 0; tt < 4; tt++) {
            const float a0 = __builtin_amdgcn_exp2f(st0[tt][0]);
            const float a1 = __builtin_amdgcn_exp2f(st0[tt][1]);
            const float a2 = __builtin_amdgcn_exp2f(st0[tt][2]);
            const float a3 = __builtin_amdgcn_exp2f(st0[tt][3]);
            cs0 += (a0 + a1) + (a2 + a3);
            uint2 pkv;
            pkv.x = pk2t(a0, a1);
            pkv.y = pk2t(a2, a3);
            *(uint2*)&Pw0[lq * 64 + (pwz ^ (tt * 16))] = pkv;
            const float b0 = __builtin_amdgcn_exp2f(st1[tt][0]);
            const float b1 = __builtin_amdgcn_exp2f(st1[tt][1]);
            const float b2 = __builtin_amdgcn_exp2f(st1[tt][2]);
            const float b3 = __builtin_amdgcn_exp2f(st1[tt][3]);
            cs1 += (b0 + b1) + (b2 + b3);
            uint2 pkw;
            pkw.x = pk2t(b0, b1);
            pkw.y = pk2t(b2, b3);
            *(uint2*)&Pw1[lq * 64 + (pwz ^ (tt * 16))] = pkw;
        }
        cs0 += __shfl_xor(cs0, 16);
        cs0 += __shfl_xor(cs0, 32);
        cs1 += __shfl_xor(cs1, 16);
        cs1 += __shfl_xor(cs1, 32);
        l0 += cs0;
        l1 += cs1;
        const s8v pb00 = *(const s8v*)&Pw0[lq * 64 + rdz0];
        const s8v pb01 = *(const s8v*)&Pw0[lq * 64 + rdz1];
        const s8v pb10 = *(const s8v*)&Pw1[lq * 64 + rdz0];
        const s8v pb11 = *(const s8v*)&Pw1[lq * 64 + rdz1];
#pragma unroll
        for (int dt = 0; dt < 4; dt++) {
            const bf16* vr = &Vp[(size_t)(dt * 16 + lq) * 1024 + t0];
            const s8v va0 = *(const s8v*)&vr[quad * 8];
            const s8v va1 = *(const s8v*)&vr[32 + quad * 8];
            o0[dt] = mfma16(va0, pb00, o0[dt]);
            o0[dt] = mfma16(va1, pb01, o0[dt]);
            o1[dt] = mfma16(va0, pb10, o1[dt]);
            o1[dt] = mfma16(va1, pb11, o1[dt]);
        }
    }
    const float i0 = 1.f / l0, i1 = 1.f / l1;
    const size_t rb0 = ((size_t)b * 1024 + q0 + lq) * 512 + h * 64;
    const size_t rb1 = rb0 + (size_t)64 * 512;
#pragma unroll
    for (int dt = 0; dt < 4; dt++) {
        uint2 ov;
        ov.x = pk2(o0[dt][0] * i0, o0[dt][1] * i0);
        ov.y = pk2(o0[dt][2] * i0, o0[dt][3] * i0);
        *(uint2*)&av[rb0 + dt * 16 + quad * 4] = ov;
        uint2 ow;
        ow.x = pk2(o1[dt][0] * i1, o1[dt][1] * i1);
        ow.y = pk2(o1[dt][2] * i1, o1[dt][3] * i1);
        *(uint2*)&av[rb1 + dt * 16 + quad * 4] = ow;
    }
}

// ---------------- layernorm: LN(A + P0 + P1 + bias) ---------------------------------------
// MODE 1: A f32, out bf16.  MODE 2: A bf16, out f32 (final).
template <int MODE>
__global__ __launch_bounds__(256)
void ln_kernel(const void* __restrict__ A, const float* __restrict__ P0,
               const float* __restrict__ P1, const float* __restrict__ bias,
               const float* __restrict__ g, const float* __restrict__ be,
               void* __restrict__ outp) {
    const int w = threadIdx.x >> 6, l = threadIdx.x & 63;
    const size_t row = (size_t)blockIdx.x * 4 + w;
    const size_t base = row * 512 + l * 8;
    float x[8];
    if (MODE == 1) {
        const float4 a0 = *(const float4*)((const float*)A + base);
        const float4 a1 = *(const float4*)((const float*)A + base + 4);
        x[0] = a0.x; x[1] = a0.y; x[2] = a0.z; x[3] = a0.w;
        x[4] = a1.x; x[5] = a1.y; x[6] = a1.z; x[7] = a1.w;
    } else {
        unpk8(*(const uint4*)((const bf16*)A + base), x);
    }
    const float4 p00 = *(const float4*)(P0 + base);
    const float4 p01 = *(const float4*)(P0 + base + 4);
    const float4 p10 = *(const float4*)(P1 + base);
    const float4 p11 = *(const float4*)(P1 + base + 4);
    const float4 bb0 = *(const float4*)(bias + l * 8);
    const float4 bb1 = *(const float4*)(bias + l * 8 + 4);
    x[0] += p00.x + p10.x + bb0.x; x[1] += p00.y + p10.y + bb0.y;
    x[2] += p00.z + p10.z + bb0.z; x[3] += p00.w + p10.w + bb0.w;
    x[4] += p01.x + p11.x + bb1.x; x[5] += p01.y + p11.y + bb1.y;
    x[6] += p01.z + p11.z + bb1.z; x[7] += p01.w + p11.w + bb1.w;
    float s = 0.f, sq = 0.f;
#pragma unroll
    for (int j = 0; j < 8; j++) { s += x[j]; sq += x[j] * x[j]; }
#pragma unroll
    for (int off = 1; off < 64; off <<= 1) {
        s += __shfl_xor(s, off);
        sq += __shfl_xor(sq, off);
    }
    const float mean = s * (1.f / 512.f);
    const float var = sq * (1.f / 512.f) - mean * mean;
    const float rstd = rsqrtf(fmaxf(var, 0.f) + 1e-5f);
    const float4 g0 = *(const float4*)(g + l * 8);
    const float4 g1 = *(const float4*)(g + l * 8 + 4);
    const float4 e0 = *(const float4*)(be + l * 8);
    const float4 e1 = *(const float4*)(be + l * 8 + 4);
    const float gv[8] = {g0.x, g0.y, g0.z, g0.w, g1.x, g1.y, g1.z, g1.w};
    const float ev[8] = {e0.x, e0.y, e0.z, e0.w, e1.x, e1.y, e1.z, e1.w};
    float y[8];
#pragma unroll
    for (int j = 0; j < 8; j++) y[j] = (x[j] - mean) * rstd * gv[j] + ev[j];
    if (MODE == 1) {
        uint4 o;
        o.x = pk2(y[0], y[1]); o.y = pk2(y[2], y[3]);
        o.z = pk2(y[4], y[5]); o.w = pk2(y[6], y[7]);
        *(uint4*)((bf16*)outp + base) = o;
    } else {
        *(float4*)((float*)outp + base)     = make_float4(y[0], y[1], y[2], y[3]);
        *(float4*)((float*)outp + base + 4) = make_float4(y[4], y[5], y[6], y[7]);
    }
}

// ---------------- host launcher ---------------------------------------------------------
extern "C" void kernel_launch(void* const* d_in, const int* in_sizes, int n_in, void* d_out,
                              int out_size, void* d_ws, size_t ws_size, hipStream_t stream) {
    const float* src = (const float*)d_in[0];
    const float* Wq = (const float*)d_in[1];
    const float* bq = (const float*)d_in[2];
    const float* Wk = (const float*)d_in[3];
    const float* bk = (const float*)d_in[4];
    const float* Wv = (const float*)d_in[5];
    const float* bv = (const float*)d_in[6];
    const float* Wo = (const float*)d_in[7];
    const float* bo = (const float*)d_in[8];
    const float* W1 = (const float*)d_in[9];
    const float* b1 = (const float*)d_in[10];
    const float* W2 = (const float*)d_in[11];
    const float* b2 = (const float*)d_in[12];
    const float* g1 = (const float*)d_in[13];
    const float* be1 = (const float*)d_in[14];
    const float* g2 = (const float*)d_in[15];
    const float* be2 = (const float*)d_in[16];
    float* out = (float*)d_out;  // reference output dtype is float32

    char* base = (char*)d_ws;
    bf16* srcb = (bf16*)(base + 0);          //  8 MB
    bf16* Qb   = (bf16*)(base + 8388608);    //  8 MB
    bf16* Kb   = (bf16*)(base + 16777216);   //  8 MB
    bf16* Vb   = (bf16*)(base + 25165824);   //  8 MB
    bf16* ff1  = (bf16*)(base + 0);          // 32 MB alias (srcb/Q/K/V dead after attn)
    bf16* avb  = (bf16*)(base + 33554432);   //  8 MB attn out; later xb (LN1 out)
    bf16* xb   = avb;                        //  alias (avb dead after Wo GEMM)
    float* saf = (float*)(base + 41943040);  // 32 MB: 2 f32 partials (Wo, then FF2)
    bf16* WqT  = (bf16*)(base + 75497472);   //  1.5 MB
    bf16* WkT  = (bf16*)(base + 77070336);   //  1.5 MB
    bf16* zp   = (bf16*)(base + 78643200);   //  1 KB
    bf16* Wvb  = (bf16*)(base + 78644224);   //  0.5 MB
    bf16* Wob  = (bf16*)(base + 79168512);   //  0.5 MB
    bf16* W1b  = (bf16*)(base + 79692800);   //  2 MB
    bf16* W2b  = (bf16*)(base + 81789952);   //  2 MB (end ~80 MB)

    prep_all<<<9728, 256, 0, stream>>>(src, Wv, Wo, W1, W2, Wq, Wk, srcb, Wvb, Wob, W1b,
                                       W2b, WqT, WkT, zp);
    conv_qk<<<dim3(8, 4, 16), 256, 0, stream>>>(srcb, WqT, WkT, bq, bk, Qb, Kb, zp);
    gemm_nt<2><<<dim3(4, 8, 8), 256, 0, stream>>>(Wvb, srcb, bv, Vb, 512, 1024, 512,
                                                  512, 512, 1024, 0, 524288, 524288);
    attn_kernel<<<dim3(64, 8), 256, 0, stream>>>(Qb, Kb, Vb, avb);
    // Wo GEMM, split-K=2 -> f32 partials
    gemm_nt<3><<<dim3(64, 4, 2), 256, 0, stream>>>(avb, Wob, nullptr, saf, 8192, 512, 256,
                                                   512, 512, 512, 256, 256, 4194304LL);
    ln_kernel<1><<<2048, 256, 0, stream>>>(src, saf, saf + 4194304, bo, g1, be1, xb);
    gemm_nt<1><<<dim3(64, 16, 1), 256, 0, stream>>>(xb, W1b, b1, ff1, 8192, 2048, 512,
                                                    512, 512, 2048, 0, 0, 0);
    // FF2 GEMM, split-K=2 -> f32 partials
    gemm_nt<3><<<dim3(64, 4, 2), 256, 0, stream>>>(ff1, W2b, nullptr, saf, 8192, 512, 1024,
                                                   2048, 2048, 512, 1024, 1024, 4194304LL);
    ln_kernel<2><<<2048, 256, 0, stream>>>(xb, saf, saf + 4194304, b2, g2, be2, out);
}

// Round 10
// 266.414 us; speedup vs baseline: 1.1253x; 1.1253x over previous
//
#include <hip/hip_runtime.h>
#include <hip/hip_bf16.h>

using bf16 = __hip_bfloat16;
typedef __attribute__((ext_vector_type(8))) short s8v;   // 8 x bf16 bits (A/B frag)
typedef __attribute__((ext_vector_type(4))) short s4v;
typedef __attribute__((ext_vector_type(4))) float f32x4; // C/D frag

#define DEV __device__ __forceinline__

DEV f32x4 mfma16(s8v a, s8v b, f32x4 c) {
    return __builtin_amdgcn_mfma_f32_16x16x32_bf16(a, b, c, 0, 0, 0);
}

DEV void gl_to_lds16(const bf16* g, bf16* l) {
    __builtin_amdgcn_global_load_lds(
        (const __attribute__((address_space(1))) void*)g,
        (__attribute__((address_space(3))) void*)l, 16, 0, 0);
}

DEV unsigned short bfbits(bf16 h) { union { bf16 h; unsigned short u; } c; c.h = h; return c.u; }
DEV unsigned pk2(float a, float b) {
    return (unsigned)bfbits(__float2bfloat16(a)) | ((unsigned)bfbits(__float2bfloat16(b)) << 16);
}
// truncation pack (round-toward-zero): 1-2 VALU; fine for nonneg P vs 2% tolerance
DEV unsigned pk2t(float a, float b) {
    return (__float_as_uint(a) >> 16) | (__float_as_uint(b) & 0xffff0000u);
}
DEV void unpk8(uint4 u, float* x) {
    const unsigned uu[4] = {u.x, u.y, u.z, u.w};
#pragma unroll
    for (int j = 0; j < 4; j++) {
        x[2 * j]     = __uint_as_float(uu[j] << 16);
        x[2 * j + 1] = __uint_as_float(uu[j] & 0xffff0000u);
    }
}

// ---------------- fused prep: f32->bf16 converts + conv-weight transpose -----------------
__global__ __launch_bounds__(256)
void prep_all(const float* __restrict__ src, const float* __restrict__ Wv,
              const float* __restrict__ Wo, const float* __restrict__ W1,
              const float* __restrict__ W2, const float* __restrict__ Wq,
              const float* __restrict__ Wk, bf16* __restrict__ srcb,
              bf16* __restrict__ Wvb, bf16* __restrict__ Wob, bf16* __restrict__ W1b,
              bf16* __restrict__ W2b, bf16* __restrict__ WqT, bf16* __restrict__ WkT,
              bf16* __restrict__ zp) {
    const int bid = blockIdx.x;
    if (bid < 6656) {
        const long long i4 = ((long long)bid * 256 + threadIdx.x) * 4;
        const float* in;
        bf16* outp;
        long long off;
        if (i4 < 4194304)      { in = src; outp = srcb; off = 0; }
        else if (i4 < 4456448) { in = Wv;  outp = Wvb;  off = 4194304; }
        else if (i4 < 4718592) { in = Wo;  outp = Wob;  off = 4456448; }
        else if (i4 < 5767168) { in = W1;  outp = W1b;  off = 4718592; }
        else                   { in = W2;  outp = W2b;  off = 5767168; }
        const long long j = i4 - off;
        const float4 v = *(const float4*)(in + j);
        uint2 o;
        o.x = pk2(v.x, v.y);
        o.y = pk2(v.z, v.w);
        *(uint2*)(outp + j) = o;
    } else {
        const int i = (bid - 6656) * 256 + threadIdx.x;
        if (i < 512) zp[i] = __float2bfloat16(0.f);
        const int dk = i >> 18, rem = i & 262143, co = rem >> 9, ci = rem & 511;
        const size_t s = (size_t)co * 1536 + ci * 3 + dk;
        WqT[i] = __float2bfloat16(Wq[s]);
        WkT[i] = __float2bfloat16(Wk[s]);
    }
}

// ---------------- conv Q/K (restructured): stage A once per ci-chunk, 3 dk passes --------
__global__ __launch_bounds__(256)
void conv_qk(const bf16* __restrict__ src, const bf16* __restrict__ WqT,
             const bf16* __restrict__ WkT, const float* __restrict__ bq,
             const float* __restrict__ bk, bf16* __restrict__ Qo, bf16* __restrict__ Ko,
             const bf16* __restrict__ zp) {
    const int z = blockIdx.z, b = z & 7, isK = z >> 3;
    const bf16* WT = isK ? WkT : WqT;
    const float* bias = isK ? bk : bq;
    bf16* out = isK ? Ko : Qo;
    const float qs = isK ? 1.0f : 0.022542109951390054f;  // log2(e)/64
    const bf16* S = src + ((size_t)b << 19);
    const int m0 = blockIdx.x * 128, n0 = blockIdx.y * 128;
    const int tid = threadIdx.x, w = tid >> 6, l = tid & 63;
    const int lq = l & 15, quad = l >> 4;
    const int wm = (w >> 1) << 6, wn = (w & 1) << 6;
    __shared__ __align__(16) bf16 As[4224], Bs[12288];
    f32x4 acc[4][4] = {};
    for (int ci0 = 0; ci0 < 512; ci0 += 32) {
        if (ci0) __syncthreads();
#pragma unroll
        for (int j = 0; j < 2; j++) {
            const int r = j * 64 + w * 16 + (l >> 2);
            const int srow = m0 - 1 + r;
            const bf16* ga = (srow >= 0 && srow < 1024)
                                 ? S + (size_t)srow * 512 + ci0 + (l & 3) * 8
                                 : zp + (l & 3) * 8;
            gl_to_lds16(ga, &As[(j * 64 + w * 16) * 32]);
        }
        if (tid < 8) {
            const int srow = m0 + 127 + (l >> 2);
            const bf16* ga = (srow < 1024) ? S + (size_t)srow * 512 + ci0 + (l & 3) * 8
                                           : zp + (l & 3) * 8;
            gl_to_lds16(ga, &As[128 * 32]);
        }
#pragma unroll
        for (int dk = 0; dk < 3; dk++)
#pragma unroll
            for (int j = 0; j < 2; j++) {
                const int co = n0 + j * 64 + w * 16 + (l >> 2);
                gl_to_lds16(WT + ((size_t)dk << 18) + (size_t)co * 512 + ci0 + (l & 3) * 8,
                            &Bs[dk * 4096 + (j * 64 + w * 16) * 32]);
            }
        __syncthreads();
#pragma unroll
        for (int dk = 0; dk < 3; dk++) {
            s8v af[4], bfv[4];
#pragma unroll
            for (int x = 0; x < 4; x++) {
                af[x]  = *(const s8v*)&As[(wm + x * 16 + lq + dk) * 32 + quad * 8];
                bfv[x] = *(const s8v*)&Bs[dk * 4096 + (wn + x * 16 + lq) * 32 + quad * 8];
            }
#pragma unroll
            for (int mt = 0; mt < 4; mt++)
#pragma unroll
                for (int nt = 0; nt < 4; nt++)
                    acc[mt][nt] = mfma16(af[mt], bfv[nt], acc[mt][nt]);
        }
    }
#pragma unroll
    for (int nt = 0; nt < 4; nt++) {
        const int co = n0 + wn + nt * 16 + lq;
        const float bn = bias[co];
        const size_t obase = ((size_t)b << 19) + ((size_t)(co >> 6) << 16) + (co & 63);
#pragma unroll
        for (int mt = 0; mt < 4; mt++)
#pragma unroll
            for (int r = 0; r < 4; r++) {
                const int s = m0 + wm + mt * 16 + quad * 4 + r;
                out[obase + (size_t)s * 64] = __float2bfloat16((acc[mt][nt][r] + bn) * qs);
            }
    }
}

// ---------------- generic NT GEMM, BK=64: C[m,n] = sum_k A[m,k]*B[n,k] -------------------
// EPI: 1 = bf16 out, bias[n], ReLU;  2 = bf16 out, bias[m];  3 = f32 partial, no bias
template <int EPI>
__global__ __launch_bounds__(256)
void gemm_nt(const bf16* __restrict__ A, const bf16* __restrict__ B,
             const float* __restrict__ bias, void* __restrict__ C, int M, int N, int K,
             int lda, int ldb, int ldc, long long aOff, long long bOff, long long cOff) {
    const int m0 = blockIdx.x * 128, n0 = blockIdx.y * 128, z = blockIdx.z;
    A += (size_t)z * aOff;
    B += (size_t)z * bOff;
    const int tid = threadIdx.x, w = tid >> 6, l = tid & 63;
    const int lq = l & 15, quad = l >> 4;
    const int wm = (w >> 1) << 6, wn = (w & 1) << 6;
    // 128 rows x 64 k each; wave-call stages 8 rows x 128B (lane l -> row l>>3, col (l&7)*8)
    __shared__ __align__(16) bf16 As[8192], Bs[8192];
    f32x4 acc[4][4] = {};
    const int srow = w * 8 + (l >> 3), scol = (l & 7) * 8;
    for (int k0 = 0; k0 < K; k0 += 64) {
        if (k0) __syncthreads();
#pragma unroll
        for (int j = 0; j < 4; j++) {
            gl_to_lds16(A + (size_t)(m0 + j * 32 + srow) * lda + k0 + scol,
                        &As[(j * 32 + w * 8) * 64]);
            gl_to_lds16(B + (size_t)(n0 + j * 32 + srow) * ldb + k0 + scol,
                        &Bs[(j * 32 + w * 8) * 64]);
        }
        __syncthreads();
#pragma unroll
        for (int ks = 0; ks < 2; ks++) {
            s8v af[4], bfv[4];
#pragma unroll
            for (int x = 0; x < 4; x++) {
                af[x]  = *(const s8v*)&As[(wm + x * 16 + lq) * 64 + ks * 32 + quad * 8];
                bfv[x] = *(const s8v*)&Bs[(wn + x * 16 + lq) * 64 + ks * 32 + quad * 8];
            }
#pragma unroll
            for (int mt = 0; mt < 4; mt++)
#pragma unroll
                for (int nt = 0; nt < 4; nt++)
                    acc[mt][nt] = mfma16(af[mt], bfv[nt], acc[mt][nt]);
        }
    }
#pragma unroll
    for (int nt = 0; nt < 4; nt++) {
        const int n = n0 + wn + nt * 16 + lq;
        const float bn = (EPI == 1) ? bias[n] : 0.f;
#pragma unroll
        for (int mt = 0; mt < 4; mt++)
#pragma unroll
            for (int r = 0; r < 4; r++) {
                const int m = m0 + wm + mt * 16 + quad * 4 + r;
                float v = acc[mt][nt][r];
                const size_t off = (size_t)z * cOff + (size_t)m * ldc + n;
                if (EPI == 3) {
                    ((float*)C)[off] = v;
                } else {
                    v += (EPI == 2) ? bias[m] : bn;
                    if (EPI == 1) v = fmaxf(v, 0.f);
                    ((bf16*)C)[off] = __float2bfloat16(v);
                }
            }
    }
}

// ---------------- flash attention (transposed-S, 2 q-frags/wave, prefetch pipeline) ------
// S^T = K·Q^T (Q pre-scaled by log2e/64): p = exp2(s). O^T = V^T·P^T.
// Grid (bh=64, qblk=8): the 8 q-blocks of one bh share an XCD slot mod 8 -> L2-local K/V.
__global__ __launch_bounds__(256)
void attn_kernel(const bf16* __restrict__ Q, const bf16* __restrict__ K,
                 const bf16* __restrict__ V, bf16* __restrict__ av) {
    const int bh = blockIdx.x, b = bh >> 3, h = bh & 7;
    const bf16* Qp = Q + ((size_t)bh << 16);  // [1024 q][64 d]
    const bf16* Kp = K + ((size_t)bh << 16);  // [1024 t][64 d]
    const bf16* Vp = V + ((size_t)bh << 16);  // [64 d][1024 t]
    const int tid = threadIdx.x, w = tid >> 6, l = tid & 63;
    const int lq = l & 15, quad = l >> 4;
    const int q0 = blockIdx.y * 128 + w * 16;   // frag0: q0, frag1: q0+64
    // XOR-swizzled: element [row][cb*8+j] stored at [row*64 + (cb^(row&7))*8 + j]
    __shared__ __align__(16) bf16 Ks[4096], Vs[4096], Ps[8192];
    bf16* Pw0 = &Ps[(w * 2 + 0) * 1024];
    bf16* Pw1 = &Ps[(w * 2 + 1) * 1024];
    const s8v qf00 = *(const s8v*)&Qp[(size_t)(q0 + lq) * 64 + quad * 8];
    const s8v qf01 = *(const s8v*)&Qp[(size_t)(q0 + lq) * 64 + 32 + quad * 8];
    const s8v qf10 = *(const s8v*)&Qp[(size_t)(q0 + 64 + lq) * 64 + quad * 8];
    const s8v qf11 = *(const s8v*)&Qp[(size_t)(q0 + 64 + lq) * 64 + 32 + quad * 8];
    f32x4 o0[4] = {}, o1[4] = {};
    float l0 = 0.f, l1 = 0.f;
    const int sr = tid >> 3;                       // staging row 0..31
    const int scb = tid & 7;                       // staging col-block
    const int swz_st = (scb ^ (sr & 7)) * 8;       // swizzled staging col offset
    const int rdz0 = (quad ^ (lq & 7)) * 8;        // frag read, cols 0..31
    const int rdz1 = ((quad + 4) ^ (lq & 7)) * 8;  // frag read, cols 32..63
    const int pwz = ((quad >> 1) ^ (lq & 7)) * 8 + (quad & 1) * 4;  // P-write base (tt=0)
    // preload tile 0 into registers
    s8v kA = *(const s8v*)&Kp[(size_t)sr * 64 + scb * 8];
    s8v kB = *(const s8v*)&Kp[(size_t)(sr + 32) * 64 + scb * 8];
    s8v vA = *(const s8v*)&Vp[(size_t)sr * 1024 + scb * 8];
    s8v vB = *(const s8v*)&Vp[(size_t)(sr + 32) * 1024 + scb * 8];
    for (int t0 = 0; t0 < 1024; t0 += 64) {
        __syncthreads();
        *(s8v*)&Ks[sr * 64 + swz_st] = kA;
        *(s8v*)&Ks[(sr + 32) * 64 + swz_st] = kB;
        *(s8v*)&Vs[sr * 64 + swz_st] = vA;
        *(s8v*)&Vs[(sr + 32) * 64 + swz_st] = vB;
        if (t0 + 64 < 1024) {  // prefetch next tile; overlaps the whole compute phase
            const int t1 = t0 + 64;
            kA = *(const s8v*)&Kp[(size_t)(t1 + sr) * 64 + scb * 8];
            kB = *(const s8v*)&Kp[(size_t)(t1 + sr + 32) * 64 + scb * 8];
            vA = *(const s8v*)&Vp[(size_t)sr * 1024 + t1 + scb * 8];
            vB = *(const s8v*)&Vp[(size_t)(sr + 32) * 1024 + t1 + scb * 8];
        }
        __syncthreads();
        f32x4 st0[4] = {}, st1[4] = {};
#pragma unroll
        for (int tt = 0; tt < 4; tt++) {
            const int rb = (tt * 16 + lq) * 64;
            const s8v ka0 = *(const s8v*)&Ks[rb + rdz0];
            const s8v ka1 = *(const s8v*)&Ks[rb + rdz1];
            st0[tt] = mfma16(ka0, qf00, st0[tt]);
            st0[tt] = mfma16(ka1, qf01, st0[tt]);
            st1[tt] = mfma16(ka0, qf10, st1[tt]);
            st1[tt] = mfma16(ka1, qf11, st1[tt]);
        }
        float cs0 = 0.f, cs1 = 0.f;
#pragma unroll
        for (int tt = 0; tt < 4; tt++) {
            const float a0 = __builtin_amdgcn_exp2f(st0[tt][0]);
            const float a1 = __builtin_amdgcn_exp2f(st0[tt][1]);
            const float a2 = __builtin_amdgcn_exp2f(st0[tt][2]);
            const float a3 = __builtin_amdgcn_exp2f(st0[tt][3]);
            cs0 += (a0 + a1) + (a2 + a3);
            uint2 pkv;
            pkv.x = pk2t(a0, a1);
            pkv.y = pk2t(a2, a3);
            *(uint2*)&Pw0[lq * 64 + (pwz ^ (tt * 16))] = pkv;
            const float b0 = __builtin_amdgcn_exp2f(st1[tt][0]);
            const float b1 = __builtin_amdgcn_exp2f(st1[tt][1]);
            const float b2 = __builtin_amdgcn_exp2f(st1[tt][2]);
            const float b3 = __builtin_amdgcn_exp2f(st1[tt][3]);
            cs1 += (b0 + b1) + (b2 + b3);
            uint2 pkw;
            pkw.x = pk2t(b0, b1);
            pkw.y = pk2t(b2, b3);
            *(uint2*)&Pw1[lq * 64 + (pwz ^ (tt * 16))] = pkw;
        }
        cs0 += __shfl_xor(cs0, 16);
        cs0 += __shfl_xor(cs0, 32);
        cs1 += __shfl_xor(cs1, 16);
        cs1 += __shfl_xor(cs1, 32);
        l0 += cs0;
        l1 += cs1;
        const s8v pb00 = *(const s8v*)&Pw0[lq * 64 + rdz0];
        const s8v pb01 = *(const s8v*)&Pw0[lq * 64 + rdz1];
        const s8v pb10 = *(const s8v*)&Pw1[lq * 64 + rdz0];
        const s8v pb11 = *(const s8v*)&Pw1[lq * 64 + rdz1];
#pragma unroll
        for (int dt = 0; dt < 4; dt++) {
            const int rb = (dt * 16 + lq) * 64;
            const s8v va0 = *(const s8v*)&Vs[rb + rdz0];
            const s8v va1 = *(const s8v*)&Vs[rb + rdz1];
            o0[dt] = mfma16(va0, pb00, o0[dt]);
            o0[dt] = mfma16(va1, pb01, o0[dt]);
            o1[dt] = mfma16(va0, pb10, o1[dt]);
            o1[dt] = mfma16(va1, pb11, o1[dt]);
        }
    }
    const float i0 = 1.f / l0, i1 = 1.f / l1;
    const size_t rb0 = ((size_t)b * 1024 + q0 + lq) * 512 + h * 64;
    const size_t rb1 = rb0 + (size_t)64 * 512;
#pragma unroll
    for (int dt = 0; dt < 4; dt++) {
        uint2 ov;
        ov.x = pk2(o0[dt][0] * i0, o0[dt][1] * i0);
        ov.y = pk2(o0[dt][2] * i0, o0[dt][3] * i0);
        *(uint2*)&av[rb0 + dt * 16 + quad * 4] = ov;
        uint2 ow;
        ow.x = pk2(o1[dt][0] * i1, o1[dt][1] * i1);
        ow.y = pk2(o1[dt][2] * i1, o1[dt][3] * i1);
        *(uint2*)&av[rb1 + dt * 16 + quad * 4] = ow;
    }
}

// ---------------- layernorm: LN(A + P0 + P1 + bias) ---------------------------------------
// MODE 1: A f32, out bf16.  MODE 2: A bf16, out f32 (final).
template <int MODE>
__global__ __launch_bounds__(256)
void ln_kernel(const void* __restrict__ A, const float* __restrict__ P0,
               const float* __restrict__ P1, const float* __restrict__ bias,
               const float* __restrict__ g, const float* __restrict__ be,
               void* __restrict__ outp) {
    const int w = threadIdx.x >> 6, l = threadIdx.x & 63;
    const size_t row = (size_t)blockIdx.x * 4 + w;
    const size_t base = row * 512 + l * 8;
    float x[8];
    if (MODE == 1) {
        const float4 a0 = *(const float4*)((const float*)A + base);
        const float4 a1 = *(const float4*)((const float*)A + base + 4);
        x[0] = a0.x; x[1] = a0.y; x[2] = a0.z; x[3] = a0.w;
        x[4] = a1.x; x[5] = a1.y; x[6] = a1.z; x[7] = a1.w;
    } else {
        unpk8(*(const uint4*)((const bf16*)A + base), x);
    }
    const float4 p00 = *(const float4*)(P0 + base);
    const float4 p01 = *(const float4*)(P0 + base + 4);
    const float4 p10 = *(const float4*)(P1 + base);
    const float4 p11 = *(const float4*)(P1 + base + 4);
    const float4 bb0 = *(const float4*)(bias + l * 8);
    const float4 bb1 = *(const float4*)(bias + l * 8 + 4);
    x[0] += p00.x + p10.x + bb0.x; x[1] += p00.y + p10.y + bb0.y;
    x[2] += p00.z + p10.z + bb0.z; x[3] += p00.w + p10.w + bb0.w;
    x[4] += p01.x + p11.x + bb1.x; x[5] += p01.y + p11.y + bb1.y;
    x[6] += p01.z + p11.z + bb1.z; x[7] += p01.w + p11.w + bb1.w;
    float s = 0.f, sq = 0.f;
#pragma unroll
    for (int j = 0; j < 8; j++) { s += x[j]; sq += x[j] * x[j]; }
#pragma unroll
    for (int off = 1; off < 64; off <<= 1) {
        s += __shfl_xor(s, off);
        sq += __shfl_xor(sq, off);
    }
    const float mean = s * (1.f / 512.f);
    const float var = sq * (1.f / 512.f) - mean * mean;
    const float rstd = rsqrtf(fmaxf(var, 0.f) + 1e-5f);
    const float4 g0 = *(const float4*)(g + l * 8);
    const float4 g1 = *(const float4*)(g + l * 8 + 4);
    const float4 e0 = *(const float4*)(be + l * 8);
    const float4 e1 = *(const float4*)(be + l * 8 + 4);
    const float gv[8] = {g0.x, g0.y, g0.z, g0.w, g1.x, g1.y, g1.z, g1.w};
    const float ev[8] = {e0.x, e0.y, e0.z, e0.w, e1.x, e1.y, e1.z, e1.w};
    float y[8];
#pragma unroll
    for (int j = 0; j < 8; j++) y[j] = (x[j] - mean) * rstd * gv[j] + ev[j];
    if (MODE == 1) {
        uint4 o;
        o.x = pk2(y[0], y[1]); o.y = pk2(y[2], y[3]);
        o.z = pk2(y[4], y[5]); o.w = pk2(y[6], y[7]);
        *(uint4*)((bf16*)outp + base) = o;
    } else {
        *(float4*)((float*)outp + base)     = make_float4(y[0], y[1], y[2], y[3]);
        *(float4*)((float*)outp + base + 4) = make_float4(y[4], y[5], y[6], y[7]);
    }
}

// ---------------- host launcher ---------------------------------------------------------
extern "C" void kernel_launch(void* const* d_in, const int* in_sizes, int n_in, void* d_out,
                              int out_size, void* d_ws, size_t ws_size, hipStream_t stream) {
    const float* src = (const float*)d_in[0];
    const float* Wq = (const float*)d_in[1];
    const float* bq = (const float*)d_in[2];
    const float* Wk = (const float*)d_in[3];
    const float* bk = (const float*)d_in[4];
    const float* Wv = (const float*)d_in[5];
    const float* bv = (const float*)d_in[6];
    const float* Wo = (const float*)d_in[7];
    const float* bo = (const float*)d_in[8];
    const float* W1 = (const float*)d_in[9];
    const float* b1 = (const float*)d_in[10];
    const float* W2 = (const float*)d_in[11];
    const float* b2 = (const float*)d_in[12];
    const float* g1 = (const float*)d_in[13];
    const float* be1 = (const float*)d_in[14];
    const float* g2 = (const float*)d_in[15];
    const float* be2 = (const float*)d_in[16];
    float* out = (float*)d_out;  // reference output dtype is float32

    char* base = (char*)d_ws;
    bf16* srcb = (bf16*)(base + 0);          //  8 MB
    bf16* Qb   = (bf16*)(base + 8388608);    //  8 MB
    bf16* Kb   = (bf16*)(base + 16777216);   //  8 MB
    bf16* Vb   = (bf16*)(base + 25165824);   //  8 MB
    bf16* ff1  = (bf16*)(base + 0);          // 32 MB alias (srcb/Q/K/V dead after attn)
    bf16* avb  = (bf16*)(base + 33554432);   //  8 MB attn out; later xb (LN1 out)
    bf16* xb   = avb;                        //  alias (avb dead after Wo GEMM)
    float* saf = (float*)(base + 41943040);  // 32 MB: 2 f32 partials (Wo, then FF2)
    bf16* WqT  = (bf16*)(base + 75497472);   //  1.5 MB
    bf16* WkT  = (bf16*)(base + 77070336);   //  1.5 MB
    bf16* zp   = (bf16*)(base + 78643200);   //  1 KB
    bf16* Wvb  = (bf16*)(base + 78644224);   //  0.5 MB
    bf16* Wob  = (bf16*)(base + 79168512);   //  0.5 MB
    bf16* W1b  = (bf16*)(base + 79692800);   //  2 MB
    bf16* W2b  = (bf16*)(base + 81789952);   //  2 MB (end ~80 MB)

    prep_all<<<9728, 256, 0, stream>>>(src, Wv, Wo, W1, W2, Wq, Wk, srcb, Wvb, Wob, W1b,
                                       W2b, WqT, WkT, zp);
    conv_qk<<<dim3(8, 4, 16), 256, 0, stream>>>(srcb, WqT, WkT, bq, bk, Qb, Kb, zp);
    gemm_nt<2><<<dim3(4, 8, 8), 256, 0, stream>>>(Wvb, srcb, bv, Vb, 512, 1024, 512,
                                                  512, 512, 1024, 0, 524288, 524288);
    attn_kernel<<<dim3(64, 8), 256, 0, stream>>>(Qb, Kb, Vb, avb);
    // Wo GEMM, split-K=2 -> f32 partials
    gemm_nt<3><<<dim3(64, 4, 2), 256, 0, stream>>>(avb, Wob, nullptr, saf, 8192, 512, 256,
                                                   512, 512, 512, 256, 256, 4194304LL);
    ln_kernel<1><<<2048, 256, 0, stream>>>(src, saf, saf + 4194304, bo, g1, be1, xb);
    gemm_nt<1><<<dim3(64, 16, 1), 256, 0, stream>>>(xb, W1b, b1, ff1, 8192, 2048, 512,
                                                    512, 512, 2048, 0, 0, 0);
    // FF2 GEMM, split-K=2 -> f32 partials
    gemm_nt<3><<<dim3(64, 4, 2), 256, 0, stream>>>(ff1, W2b, nullptr, saf, 8192, 512, 1024,
                                                   2048, 2048, 512, 1024, 1024, 4194304LL);
    ln_kernel<2><<<2048, 256, 0, stream>>>(xb, saf, saf + 4194304, b2, g2, be2, out);
}

// Round 11
// 260.968 us; speedup vs baseline: 1.1488x; 1.0209x over previous
//
#include <hip/hip_runtime.h>
#include <hip/hip_bf16.h>

using bf16 = __hip_bfloat16;
typedef __attribute__((ext_vector_type(8))) short s8v;   // 8 x bf16 bits (A/B frag)
typedef __attribute__((ext_vector_type(4))) short s4v;
typedef __attribute__((ext_vector_type(4))) float f32x4; // C/D frag

#define DEV __device__ __forceinline__

DEV f32x4 mfma16(s8v a, s8v b, f32x4 c) {
    return __builtin_amdgcn_mfma_f32_16x16x32_bf16(a, b, c, 0, 0, 0);
}

DEV void gl_to_lds16(const bf16* g, bf16* l) {
    __builtin_amdgcn_global_load_lds(
        (const __attribute__((address_space(1))) void*)g,
        (__attribute__((address_space(3))) void*)l, 16, 0, 0);
}

DEV unsigned short bfbits(bf16 h) { union { bf16 h; unsigned short u; } c; c.h = h; return c.u; }
DEV unsigned pk2(float a, float b) {
    return (unsigned)bfbits(__float2bfloat16(a)) | ((unsigned)bfbits(__float2bfloat16(b)) << 16);
}
// truncation pack (round-toward-zero): 1-2 VALU; fine for nonneg P vs 2% tolerance
DEV unsigned pk2t(float a, float b) {
    return (__float_as_uint(a) >> 16) | (__float_as_uint(b) & 0xffff0000u);
}
DEV void unpk8(uint4 u, float* x) {
    const unsigned uu[4] = {u.x, u.y, u.z, u.w};
#pragma unroll
    for (int j = 0; j < 4; j++) {
        x[2 * j]     = __uint_as_float(uu[j] << 16);
        x[2 * j + 1] = __uint_as_float(uu[j] & 0xffff0000u);
    }
}

// ---------------- fused prep: f32->bf16 converts + conv-weight transpose -----------------
__global__ __launch_bounds__(256)
void prep_all(const float* __restrict__ src, const float* __restrict__ Wv,
              const float* __restrict__ Wo, const float* __restrict__ W1,
              const float* __restrict__ W2, const float* __restrict__ Wq,
              const float* __restrict__ Wk, bf16* __restrict__ srcb,
              bf16* __restrict__ Wvb, bf16* __restrict__ Wob, bf16* __restrict__ W1b,
              bf16* __restrict__ W2b, bf16* __restrict__ WqT, bf16* __restrict__ WkT,
              bf16* __restrict__ zp) {
    const int bid = blockIdx.x;
    if (bid < 6656) {
        const long long i4 = ((long long)bid * 256 + threadIdx.x) * 4;
        const float* in;
        bf16* outp;
        long long off;
        if (i4 < 4194304)      { in = src; outp = srcb; off = 0; }
        else if (i4 < 4456448) { in = Wv;  outp = Wvb;  off = 4194304; }
        else if (i4 < 4718592) { in = Wo;  outp = Wob;  off = 4456448; }
        else if (i4 < 5767168) { in = W1;  outp = W1b;  off = 4718592; }
        else                   { in = W2;  outp = W2b;  off = 5767168; }
        const long long j = i4 - off;
        const float4 v = *(const float4*)(in + j);
        uint2 o;
        o.x = pk2(v.x, v.y);
        o.y = pk2(v.z, v.w);
        *(uint2*)(outp + j) = o;
    } else {
        const int i = (bid - 6656) * 256 + threadIdx.x;
        if (i < 512) zp[i] = __float2bfloat16(0.f);
        const int dk = i >> 18, rem = i & 262143, co = rem >> 9, ci = rem & 511;
        const size_t s = (size_t)co * 1536 + ci * 3 + dk;
        WqT[i] = __float2bfloat16(Wq[s]);
        WkT[i] = __float2bfloat16(Wk[s]);
    }
}

// ---------------- fused conv Q/K + V GEMM: z<16 conv (b,isK), z>=16 V gemm (b=z-16) ------
// conv: out[s,co] = sum_{dk,ci} src[s-1+dk,ci]*WT[dk][co][ci] + bias (Q pre-scaled)
// V:    V[b][m][n] = sum_k Wv[m,k]*src[b][n,k] + bv[m]   (m=d 0..511, n=s 0..1023)
__global__ __launch_bounds__(256)
void conv_v(const bf16* __restrict__ src, const bf16* __restrict__ WqT,
            const bf16* __restrict__ WkT, const float* __restrict__ bq,
            const float* __restrict__ bk, bf16* __restrict__ Qo, bf16* __restrict__ Ko,
            const bf16* __restrict__ zp, const bf16* __restrict__ Wvb,
            const float* __restrict__ bv, bf16* __restrict__ Vb) {
    const int z = blockIdx.z;
    const int tid = threadIdx.x, w = tid >> 6, l = tid & 63;
    const int lq = l & 15, quad = l >> 4;
    const int wm = (w >> 1) << 6, wn = (w & 1) << 6;
    __shared__ __align__(16) bf16 smem[16896];  // 33 KB union: conv 16512, V 16384 elems
    if (z < 16) {
        const int b = z & 7, isK = z >> 3;
        const bf16* WT = isK ? WkT : WqT;
        const float* bias = isK ? bk : bq;
        bf16* out = isK ? Ko : Qo;
        const float qs = isK ? 1.0f : 0.022542109951390054f;  // log2(e)/64
        const bf16* S = src + ((size_t)b << 19);
        const int m0 = blockIdx.x * 128, n0 = blockIdx.y * 128;
        bf16* As = smem;          // 130 rows x 32
        bf16* Bs = smem + 4224;   // 3 dk x 128 co x 32
        f32x4 acc[4][4] = {};
        for (int ci0 = 0; ci0 < 512; ci0 += 32) {
            if (ci0) __syncthreads();
#pragma unroll
            for (int j = 0; j < 2; j++) {
                const int r = j * 64 + w * 16 + (l >> 2);
                const int srow = m0 - 1 + r;
                const bf16* ga = (srow >= 0 && srow < 1024)
                                     ? S + (size_t)srow * 512 + ci0 + (l & 3) * 8
                                     : zp + (l & 3) * 8;
                gl_to_lds16(ga, &As[(j * 64 + w * 16) * 32]);
            }
            if (tid < 8) {
                const int srow = m0 + 127 + (l >> 2);
                const bf16* ga = (srow < 1024) ? S + (size_t)srow * 512 + ci0 + (l & 3) * 8
                                               : zp + (l & 3) * 8;
                gl_to_lds16(ga, &As[128 * 32]);
            }
#pragma unroll
            for (int dk = 0; dk < 3; dk++)
#pragma unroll
                for (int j = 0; j < 2; j++) {
                    const int co = n0 + j * 64 + w * 16 + (l >> 2);
                    gl_to_lds16(WT + ((size_t)dk << 18) + (size_t)co * 512 + ci0 + (l & 3) * 8,
                                &Bs[dk * 4096 + (j * 64 + w * 16) * 32]);
                }
            __syncthreads();
#pragma unroll
            for (int dk = 0; dk < 3; dk++) {
                s8v af[4], bfv[4];
#pragma unroll
                for (int x = 0; x < 4; x++) {
                    af[x]  = *(const s8v*)&As[(wm + x * 16 + lq + dk) * 32 + quad * 8];
                    bfv[x] = *(const s8v*)&Bs[dk * 4096 + (wn + x * 16 + lq) * 32 + quad * 8];
                }
#pragma unroll
                for (int mt = 0; mt < 4; mt++)
#pragma unroll
                    for (int nt = 0; nt < 4; nt++)
                        acc[mt][nt] = mfma16(af[mt], bfv[nt], acc[mt][nt]);
            }
        }
#pragma unroll
        for (int nt = 0; nt < 4; nt++) {
            const int co = n0 + wn + nt * 16 + lq;
            const float bn = bias[co];
            const size_t obase = ((size_t)b << 19) + ((size_t)(co >> 6) << 16) + (co & 63);
#pragma unroll
            for (int mt = 0; mt < 4; mt++)
#pragma unroll
                for (int r = 0; r < 4; r++) {
                    const int s = m0 + wm + mt * 16 + quad * 4 + r;
                    out[obase + (size_t)s * 64] = __float2bfloat16((acc[mt][nt][r] + bn) * qs);
                }
        }
    } else {
        // V GEMM: BK=64; m0 from y (4 blocks, M=512), n0 from x (8 blocks, N=1024)
        const int b = z - 16;
        const bf16* A = Wvb;
        const bf16* B = src + (size_t)b * 524288;
        bf16* C = Vb + (size_t)b * 524288;
        const int m0 = blockIdx.y * 128, n0 = blockIdx.x * 128;
        bf16* As = smem;
        bf16* Bs = smem + 8192;
        f32x4 acc[4][4] = {};
        const int srow = w * 8 + (l >> 3), scol = (l & 7) * 8;
        for (int k0 = 0; k0 < 512; k0 += 64) {
            if (k0) __syncthreads();
#pragma unroll
            for (int j = 0; j < 4; j++) {
                gl_to_lds16(A + (size_t)(m0 + j * 32 + srow) * 512 + k0 + scol,
                            &As[(j * 32 + w * 8) * 64]);
                gl_to_lds16(B + (size_t)(n0 + j * 32 + srow) * 512 + k0 + scol,
                            &Bs[(j * 32 + w * 8) * 64]);
            }
            __syncthreads();
#pragma unroll
            for (int ks = 0; ks < 2; ks++) {
                s8v af[4], bfv[4];
#pragma unroll
                for (int x = 0; x < 4; x++) {
                    af[x]  = *(const s8v*)&As[(wm + x * 16 + lq) * 64 + ks * 32 + quad * 8];
                    bfv[x] = *(const s8v*)&Bs[(wn + x * 16 + lq) * 64 + ks * 32 + quad * 8];
                }
#pragma unroll
                for (int mt = 0; mt < 4; mt++)
#pragma unroll
                    for (int nt = 0; nt < 4; nt++)
                        acc[mt][nt] = mfma16(af[mt], bfv[nt], acc[mt][nt]);
            }
        }
#pragma unroll
        for (int nt = 0; nt < 4; nt++) {
            const int n = n0 + wn + nt * 16 + lq;
#pragma unroll
            for (int mt = 0; mt < 4; mt++)
#pragma unroll
                for (int r = 0; r < 4; r++) {
                    const int m = m0 + wm + mt * 16 + quad * 4 + r;
                    C[(size_t)m * 1024 + n] = __float2bfloat16(acc[mt][nt][r] + bv[m]);
                }
        }
    }
}

// ---------------- generic NT GEMM, BK=64: C[m,n] = sum_k A[m,k]*B[n,k] -------------------
// EPI: 1 = bf16 out, bias[n], ReLU;  3 = f32 partial, no bias
template <int EPI>
__global__ __launch_bounds__(256)
void gemm_nt(const bf16* __restrict__ A, const bf16* __restrict__ B,
             const float* __restrict__ bias, void* __restrict__ C, int M, int N, int K,
             int lda, int ldb, int ldc, long long aOff, long long bOff, long long cOff) {
    const int m0 = blockIdx.x * 128, n0 = blockIdx.y * 128, z = blockIdx.z;
    A += (size_t)z * aOff;
    B += (size_t)z * bOff;
    const int tid = threadIdx.x, w = tid >> 6, l = tid & 63;
    const int lq = l & 15, quad = l >> 4;
    const int wm = (w >> 1) << 6, wn = (w & 1) << 6;
    __shared__ __align__(16) bf16 As[8192], Bs[8192];
    f32x4 acc[4][4] = {};
    const int srow = w * 8 + (l >> 3), scol = (l & 7) * 8;
    for (int k0 = 0; k0 < K; k0 += 64) {
        if (k0) __syncthreads();
#pragma unroll
        for (int j = 0; j < 4; j++) {
            gl_to_lds16(A + (size_t)(m0 + j * 32 + srow) * lda + k0 + scol,
                        &As[(j * 32 + w * 8) * 64]);
            gl_to_lds16(B + (size_t)(n0 + j * 32 + srow) * ldb + k0 + scol,
                        &Bs[(j * 32 + w * 8) * 64]);
        }
        __syncthreads();
#pragma unroll
        for (int ks = 0; ks < 2; ks++) {
            s8v af[4], bfv[4];
#pragma unroll
            for (int x = 0; x < 4; x++) {
                af[x]  = *(const s8v*)&As[(wm + x * 16 + lq) * 64 + ks * 32 + quad * 8];
                bfv[x] = *(const s8v*)&Bs[(wn + x * 16 + lq) * 64 + ks * 32 + quad * 8];
            }
#pragma unroll
            for (int mt = 0; mt < 4; mt++)
#pragma unroll
                for (int nt = 0; nt < 4; nt++)
                    acc[mt][nt] = mfma16(af[mt], bfv[nt], acc[mt][nt]);
        }
    }
#pragma unroll
    for (int nt = 0; nt < 4; nt++) {
        const int n = n0 + wn + nt * 16 + lq;
        const float bn = (EPI == 1) ? bias[n] : 0.f;
#pragma unroll
        for (int mt = 0; mt < 4; mt++)
#pragma unroll
            for (int r = 0; r < 4; r++) {
                const int m = m0 + wm + mt * 16 + quad * 4 + r;
                float v = acc[mt][nt][r];
                const size_t off = (size_t)z * cOff + (size_t)m * ldc + n;
                if (EPI == 3) {
                    ((float*)C)[off] = v;
                } else {
                    v += bn;
                    if (EPI == 1) v = fmaxf(v, 0.f);
                    ((bf16*)C)[off] = __float2bfloat16(v);
                }
            }
    }
}

// ---------------- flash attention (transposed-S, 1 q-frag/wave, prefetch, grid 64x16) ----
// S^T = K·Q^T (Q pre-scaled by log2e/64): p = exp2(s). O^T = V^T·P^T.
// 1024 blocks -> 4 blocks/CU -> 4 waves/SIMD for latency hiding.
__global__ __launch_bounds__(256)
void attn_kernel(const bf16* __restrict__ Q, const bf16* __restrict__ K,
                 const bf16* __restrict__ V, bf16* __restrict__ av) {
    const int bh = blockIdx.x, b = bh >> 3, h = bh & 7;
    const bf16* Qp = Q + ((size_t)bh << 16);  // [1024 q][64 d]
    const bf16* Kp = K + ((size_t)bh << 16);  // [1024 t][64 d]
    const bf16* Vp = V + ((size_t)bh << 16);  // [64 d][1024 t]
    const int tid = threadIdx.x, w = tid >> 6, l = tid & 63;
    const int lq = l & 15, quad = l >> 4;
    const int q0 = blockIdx.y * 64 + w * 16;
    // XOR-swizzled: element [row][cb*8+j] stored at [row*64 + (cb^(row&7))*8 + j]
    __shared__ __align__(16) bf16 Ks[4096], Vs[4096], Ps[4096];
    bf16* Pw = &Ps[w * 1024];
    const s8v qf0 = *(const s8v*)&Qp[(size_t)(q0 + lq) * 64 + quad * 8];
    const s8v qf1 = *(const s8v*)&Qp[(size_t)(q0 + lq) * 64 + 32 + quad * 8];
    f32x4 o[4] = {};
    float l0 = 0.f;
    const int sr = tid >> 3;                       // staging row 0..31
    const int scb = tid & 7;                       // staging col-block
    const int swz_st = (scb ^ (sr & 7)) * 8;       // swizzled staging col offset
    const int rdz0 = (quad ^ (lq & 7)) * 8;        // frag read, cols 0..31
    const int rdz1 = ((quad + 4) ^ (lq & 7)) * 8;  // frag read, cols 32..63
    const int pwz = ((quad >> 1) ^ (lq & 7)) * 8 + (quad & 1) * 4;  // P-write base (tt=0)
    // preload tile 0 into registers
    s8v kA = *(const s8v*)&Kp[(size_t)sr * 64 + scb * 8];
    s8v kB = *(const s8v*)&Kp[(size_t)(sr + 32) * 64 + scb * 8];
    s8v vA = *(const s8v*)&Vp[(size_t)sr * 1024 + scb * 8];
    s8v vB = *(const s8v*)&Vp[(size_t)(sr + 32) * 1024 + scb * 8];
    for (int t0 = 0; t0 < 1024; t0 += 64) {
        __syncthreads();
        *(s8v*)&Ks[sr * 64 + swz_st] = kA;
        *(s8v*)&Ks[(sr + 32) * 64 + swz_st] = kB;
        *(s8v*)&Vs[sr * 64 + swz_st] = vA;
        *(s8v*)&Vs[(sr + 32) * 64 + swz_st] = vB;
        if (t0 + 64 < 1024) {  // prefetch next tile; overlaps the whole compute phase
            const int t1 = t0 + 64;
            kA = *(const s8v*)&Kp[(size_t)(t1 + sr) * 64 + scb * 8];
            kB = *(const s8v*)&Kp[(size_t)(t1 + sr + 32) * 64 + scb * 8];
            vA = *(const s8v*)&Vp[(size_t)sr * 1024 + t1 + scb * 8];
            vB = *(const s8v*)&Vp[(size_t)(sr + 32) * 1024 + t1 + scb * 8];
        }
        __syncthreads();
        f32x4 st[4] = {};
#pragma unroll
        for (int tt = 0; tt < 4; tt++) {
            const int rb = (tt * 16 + lq) * 64;
            const s8v ka0 = *(const s8v*)&Ks[rb + rdz0];
            const s8v ka1 = *(const s8v*)&Ks[rb + rdz1];
            st[tt] = mfma16(ka0, qf0, st[tt]);
            st[tt] = mfma16(ka1, qf1, st[tt]);
        }
        float cs0 = 0.f;
#pragma unroll
        for (int tt = 0; tt < 4; tt++) {
            const float a0 = __builtin_amdgcn_exp2f(st[tt][0]);
            const float a1 = __builtin_amdgcn_exp2f(st[tt][1]);
            const float a2 = __builtin_amdgcn_exp2f(st[tt][2]);
            const float a3 = __builtin_amdgcn_exp2f(st[tt][3]);
            cs0 += (a0 + a1) + (a2 + a3);
            uint2 pkv;
            pkv.x = pk2t(a0, a1);
            pkv.y = pk2t(a2, a3);
            *(uint2*)&Pw[lq * 64 + (pwz ^ (tt * 16))] = pkv;
        }
        cs0 += __shfl_xor(cs0, 16);
        cs0 += __shfl_xor(cs0, 32);
        l0 += cs0;
        const s8v pb0 = *(const s8v*)&Pw[lq * 64 + rdz0];
        const s8v pb1 = *(const s8v*)&Pw[lq * 64 + rdz1];
#pragma unroll
        for (int dt = 0; dt < 4; dt++) {
            const int rb = (dt * 16 + lq) * 64;
            const s8v va0 = *(const s8v*)&Vs[rb + rdz0];
            const s8v va1 = *(const s8v*)&Vs[rb + rdz1];
            o[dt] = mfma16(va0, pb0, o[dt]);
            o[dt] = mfma16(va1, pb1, o[dt]);
        }
    }
    const float i0 = 1.f / l0;
    const size_t rb0 = ((size_t)b * 1024 + q0 + lq) * 512 + h * 64;
#pragma unroll
    for (int dt = 0; dt < 4; dt++) {
        uint2 ov;
        ov.x = pk2(o[dt][0] * i0, o[dt][1] * i0);
        ov.y = pk2(o[dt][2] * i0, o[dt][3] * i0);
        *(uint2*)&av[rb0 + dt * 16 + quad * 4] = ov;
    }
}

// ---------------- layernorm: LN(A + P0 + P1 + bias) ---------------------------------------
// MODE 1: A f32, out bf16.  MODE 2: A bf16, out f32 (final).
template <int MODE>
__global__ __launch_bounds__(256)
void ln_kernel(const void* __restrict__ A, const float* __restrict__ P0,
               const float* __restrict__ P1, const float* __restrict__ bias,
               const float* __restrict__ g, const float* __restrict__ be,
               void* __restrict__ outp) {
    const int w = threadIdx.x >> 6, l = threadIdx.x & 63;
    const size_t row = (size_t)blockIdx.x * 4 + w;
    const size_t base = row * 512 + l * 8;
    float x[8];
    if (MODE == 1) {
        const float4 a0 = *(const float4*)((const float*)A + base);
        const float4 a1 = *(const float4*)((const float*)A + base + 4);
        x[0] = a0.x; x[1] = a0.y; x[2] = a0.z; x[3] = a0.w;
        x[4] = a1.x; x[5] = a1.y; x[6] = a1.z; x[7] = a1.w;
    } else {
        unpk8(*(const uint4*)((const bf16*)A + base), x);
    }
    const float4 p00 = *(const float4*)(P0 + base);
    const float4 p01 = *(const float4*)(P0 + base + 4);
    const float4 p10 = *(const float4*)(P1 + base);
    const float4 p11 = *(const float4*)(P1 + base + 4);
    const float4 bb0 = *(const float4*)(bias + l * 8);
    const float4 bb1 = *(const float4*)(bias + l * 8 + 4);
    x[0] += p00.x + p10.x + bb0.x; x[1] += p00.y + p10.y + bb0.y;
    x[2] += p00.z + p10.z + bb0.z; x[3] += p00.w + p10.w + bb0.w;
    x[4] += p01.x + p11.x + bb1.x; x[5] += p01.y + p11.y + bb1.y;
    x[6] += p01.z + p11.z + bb1.z; x[7] += p01.w + p11.w + bb1.w;
    float s = 0.f, sq = 0.f;
#pragma unroll
    for (int j = 0; j < 8; j++) { s += x[j]; sq += x[j] * x[j]; }
#pragma unroll
    for (int off = 1; off < 64; off <<= 1) {
        s += __shfl_xor(s, off);
        sq += __shfl_xor(sq, off);
    }
    const float mean = s * (1.f / 512.f);
    const float var = sq * (1.f / 512.f) - mean * mean;
    const float rstd = rsqrtf(fmaxf(var, 0.f) + 1e-5f);
    const float4 g0 = *(const float4*)(g + l * 8);
    const float4 g1 = *(const float4*)(g + l * 8 + 4);
    const float4 e0 = *(const float4*)(be + l * 8);
    const float4 e1 = *(const float4*)(be + l * 8 + 4);
    const float gv[8] = {g0.x, g0.y, g0.z, g0.w, g1.x, g1.y, g1.z, g1.w};
    const float ev[8] = {e0.x, e0.y, e0.z, e0.w, e1.x, e1.y, e1.z, e1.w};
    float y[8];
#pragma unroll
    for (int j = 0; j < 8; j++) y[j] = (x[j] - mean) * rstd * gv[j] + ev[j];
    if (MODE == 1) {
        uint4 o;
        o.x = pk2(y[0], y[1]); o.y = pk2(y[2], y[3]);
        o.z = pk2(y[4], y[5]); o.w = pk2(y[6], y[7]);
        *(uint4*)((bf16*)outp + base) = o;
    } else {
        *(float4*)((float*)outp + base)     = make_float4(y[0], y[1], y[2], y[3]);
        *(float4*)((float*)outp + base + 4) = make_float4(y[4], y[5], y[6], y[7]);
    }
}

// ---------------- host launcher ---------------------------------------------------------
extern "C" void kernel_launch(void* const* d_in, const int* in_sizes, int n_in, void* d_out,
                              int out_size, void* d_ws, size_t ws_size, hipStream_t stream) {
    const float* src = (const float*)d_in[0];
    const float* Wq = (const float*)d_in[1];
    const float* bq = (const float*)d_in[2];
    const float* Wk = (const float*)d_in[3];
    const float* bk = (const float*)d_in[4];
    const float* Wv = (const float*)d_in[5];
    const float* bv = (const float*)d_in[6];
    const float* Wo = (const float*)d_in[7];
    const float* bo = (const float*)d_in[8];
    const float* W1 = (const float*)d_in[9];
    const float* b1 = (const float*)d_in[10];
    const float* W2 = (const float*)d_in[11];
    const float* b2 = (const float*)d_in[12];
    const float* g1 = (const float*)d_in[13];
    const float* be1 = (const float*)d_in[14];
    const float* g2 = (const float*)d_in[15];
    const float* be2 = (const float*)d_in[16];
    float* out = (float*)d_out;  // reference output dtype is float32

    char* base = (char*)d_ws;
    bf16* srcb = (bf16*)(base + 0);          //  8 MB
    bf16* Qb   = (bf16*)(base + 8388608);    //  8 MB
    bf16* Kb   = (bf16*)(base + 16777216);   //  8 MB
    bf16* Vb   = (bf16*)(base + 25165824);   //  8 MB
    bf16* ff1  = (bf16*)(base + 0);          // 32 MB alias (srcb/Q/K/V dead after attn)
    bf16* avb  = (bf16*)(base + 33554432);   //  8 MB attn out; later xb (LN1 out)
    bf16* xb   = avb;                        //  alias (avb dead after Wo GEMM)
    float* saf = (float*)(base + 41943040);  // 32 MB: 2 f32 partials (Wo, then FF2)
    bf16* WqT  = (bf16*)(base + 75497472);   //  1.5 MB
    bf16* WkT  = (bf16*)(base + 77070336);   //  1.5 MB
    bf16* zp   = (bf16*)(base + 78643200);   //  1 KB
    bf16* Wvb  = (bf16*)(base + 78644224);   //  0.5 MB
    bf16* Wob  = (bf16*)(base + 79168512);   //  0.5 MB
    bf16* W1b  = (bf16*)(base + 79692800);   //  2 MB
    bf16* W2b  = (bf16*)(base + 81789952);   //  2 MB (end ~80 MB)

    prep_all<<<9728, 256, 0, stream>>>(src, Wv, Wo, W1, W2, Wq, Wk, srcb, Wvb, Wob, W1b,
                                       W2b, WqT, WkT, zp);
    // fused conv Q/K (z<16) + V GEMM (z>=16)
    conv_v<<<dim3(8, 4, 24), 256, 0, stream>>>(srcb, WqT, WkT, bq, bk, Qb, Kb, zp,
                                               Wvb, bv, Vb);
    attn_kernel<<<dim3(64, 16), 256, 0, stream>>>(Qb, Kb, Vb, avb);
    // Wo GEMM, split-K=2 -> f32 partials
    gemm_nt<3><<<dim3(64, 4, 2), 256, 0, stream>>>(avb, Wob, nullptr, saf, 8192, 512, 256,
                                                   512, 512, 512, 256, 256, 4194304LL);
    ln_kernel<1><<<2048, 256, 0, stream>>>(src, saf, saf + 4194304, bo, g1, be1, xb);
    gemm_nt<1><<<dim3(64, 16, 1), 256, 0, stream>>>(xb, W1b, b1, ff1, 8192, 2048, 512,
                                                    512, 512, 2048, 0, 0, 0);
    // FF2 GEMM, split-K=2 -> f32 partials
    gemm_nt<3><<<dim3(64, 4, 2), 256, 0, stream>>>(ff1, W2b, nullptr, saf, 8192, 512, 1024,
                                                   2048, 2048, 512, 1024, 1024, 4194304LL);
    ln_kernel<2><<<2048, 256, 0, stream>>>(xb, saf, saf + 4194304, b2, g2, be2, out);
}